// Round 1
// baseline (163.313 us; speedup 1.0000x reference)
//
#include <hip/hip_runtime.h>
#include <hip/hip_bf16.h>

#ifndef __has_builtin
#define __has_builtin(x) 0
#endif

// ---- problem constants (from reference) ----
constexpr int B_ = 8, TE_ = 512, TD_ = 128, H_ = 256;
constexpr float TWO_LOG2E = 2.8853900817779268f;   // 2*log2(e)
constexpr float LOG2E = 1.4426950408889634f;

__device__ __forceinline__ float exp2_fast(float x) {
#if __has_builtin(__builtin_amdgcn_exp2f)
  return __builtin_amdgcn_exp2f(x);     // v_exp_f32
#else
  return __expf(x * 0.69314718055994531f);
#endif
}

__device__ __forceinline__ float rcp_fast(float x) {
#if __has_builtin(__builtin_amdgcn_rcpf)
  return __builtin_amdgcn_rcpf(x);      // v_rcp_f32, ~1 ulp
#else
  return 1.0f / x;
#endif
}

// ---------------- generic fp32 tiled GEMM (row-major, exact sizes) ----------------
// C[M,N] = A[M,K] @ B[K,N], batched via blockIdx.z with element strides sA/sB/sC.
template<int BM, int BN, int BK, int TM, int TN>
__global__ __launch_bounds__(256)
void gemm_f32(const float* __restrict__ A, const float* __restrict__ Bm,
              float* __restrict__ C, int M, int N, int K,
              long sA, long sB, long sC) {
  constexpr int TCOLS = BN / TN;
  constexpr int TROWS = BM / TM;
  static_assert(TCOLS * TROWS == 256, "need 256 threads");
  __shared__ __align__(16) float As[BK][BM + 4];  // k-major: As[k][m]
  __shared__ __align__(16) float Bs[BK][BN + 4];  // Bs[k][n]
  const int tid = threadIdx.x;
  const int tx = tid % TCOLS;
  const int ty = tid / TCOLS;
  const float* Ab = A + (long)blockIdx.z * sA;
  const float* Bb = Bm + (long)blockIdx.z * sB;
  float* Cb = C + (long)blockIdx.z * sC;
  const int row0 = blockIdx.x * BM;
  const int col0 = blockIdx.y * BN;

  float acc[TM][TN];
#pragma unroll
  for (int m = 0; m < TM; ++m)
#pragma unroll
    for (int n = 0; n < TN; ++n) acc[m][n] = 0.f;

  for (int k0 = 0; k0 < K; k0 += BK) {
    // stage A tile (transpose to k-major)
    for (int i = tid; i < BM * BK / 4; i += 256) {
      int r = i / (BK / 4);
      int kg = (i % (BK / 4)) * 4;
      float4 a4 = *(const float4*)&Ab[(long)(row0 + r) * K + k0 + kg];
      As[kg + 0][r] = a4.x;
      As[kg + 1][r] = a4.y;
      As[kg + 2][r] = a4.z;
      As[kg + 3][r] = a4.w;
    }
    // stage B tile (already k-major)
    for (int i = tid; i < BK * BN / 4; i += 256) {
      int kk = i / (BN / 4);
      int c = (i % (BN / 4)) * 4;
      *(float4*)&Bs[kk][c] = *(const float4*)&Bb[(long)(k0 + kk) * N + col0 + c];
    }
    __syncthreads();
#pragma unroll
    for (int kk = 0; kk < BK; ++kk) {
      float af[TM], bf[TN];
      if constexpr (TM == 4) {
        float4 a = *(const float4*)&As[kk][ty * 4];
        af[0] = a.x; af[1] = a.y; af[2] = a.z; af[3] = a.w;
      } else {
#pragma unroll
        for (int m = 0; m < TM; ++m) af[m] = As[kk][ty * TM + m];
      }
      if constexpr (TN == 4) {
        float4 b = *(const float4*)&Bs[kk][tx * 4];
        bf[0] = b.x; bf[1] = b.y; bf[2] = b.z; bf[3] = b.w;
      } else {
#pragma unroll
        for (int n = 0; n < TN; ++n) bf[n] = Bs[kk][tx * TN + n];
      }
#pragma unroll
      for (int m = 0; m < TM; ++m)
#pragma unroll
        for (int n = 0; n < TN; ++n) acc[m][n] = __fmaf_rn(af[m], bf[n], acc[m][n]);
    }
    __syncthreads();
  }
#pragma unroll
  for (int m = 0; m < TM; ++m) {
    long crow = (long)(row0 + ty * TM + m) * N + col0;
    if constexpr (TN == 4) {
      float4 o;
      o.x = acc[m][0]; o.y = acc[m][1]; o.z = acc[m][2]; o.w = acc[m][3];
      *(float4*)&Cb[crow + tx * 4] = o;
    } else {
#pragma unroll
      for (int n = 0; n < TN; ++n) Cb[crow + tx * TN + n] = acc[m][n];
    }
  }
}

// ---------------- score kernel: score[b,d,e] = sum_h tanh(ep+dp)*v ----------------
// grid: (TE/32, TD/32, B), block: 256. Thread handles 1 e-col x 4 d-rows.
__global__ __launch_bounds__(256)
void score_kernel(const float* __restrict__ ep, const float* __restrict__ dp,
                  const float* __restrict__ v, float* __restrict__ score) {
  __shared__ __align__(16) float eps[32][68];  // [e][h-chunk], pad 4 keeps 16B align
  __shared__ __align__(16) float dps[32][68];  // [d][h-chunk]
  __shared__ __align__(16) float vs[64];
  const int tid = threadIdx.x;
  const int b = blockIdx.z;
  const int e0 = blockIdx.x * 32;
  const int d0 = blockIdx.y * 32;
  const int e = tid & 31;
  const int dg = tid >> 5;  // 0..7 -> 4 d-rows each
  float acc[4] = {0.f, 0.f, 0.f, 0.f};

  for (int h0 = 0; h0 < H_; h0 += 64) {
    for (int i = tid; i < 512; i += 256) {       // 32 rows x 16 float4
      int r = i >> 4;
      int c = (i & 15) << 2;
      *(float4*)&eps[r][c] = *(const float4*)&ep[((long)(b * TE_ + e0 + r)) * H_ + h0 + c];
    }
    for (int i = tid; i < 512; i += 256) {
      int r = i >> 4;
      int c = (i & 15) << 2;
      *(float4*)&dps[r][c] = *(const float4*)&dp[((long)(b * TD_ + d0 + r)) * H_ + h0 + c];
    }
    if (tid < 16) *(float4*)&vs[tid * 4] = *(const float4*)&v[h0 + tid * 4];
    __syncthreads();
#pragma unroll
    for (int hh = 0; hh < 64; hh += 4) {
      float4 epv = *(const float4*)&eps[e][hh];
      float4 vv = *(const float4*)&vs[hh];
      // pre-scale ep by 2*log2e once, shared across the 4 d-rows
      float4 ec;
      ec.x = epv.x * TWO_LOG2E; ec.y = epv.y * TWO_LOG2E;
      ec.z = epv.z * TWO_LOG2E; ec.w = epv.w * TWO_LOG2E;
#pragma unroll
      for (int j = 0; j < 4; ++j) {
        float4 dv = *(const float4*)&dps[dg * 4 + j][hh];
        float t, s;
        t = exp2_fast(__fmaf_rn(dv.x, TWO_LOG2E, ec.x));
        s = __fmaf_rn(-2.f, rcp_fast(t + 1.f), 1.f);      // tanh
        acc[j] = __fmaf_rn(vv.x, s, acc[j]);
        t = exp2_fast(__fmaf_rn(dv.y, TWO_LOG2E, ec.y));
        s = __fmaf_rn(-2.f, rcp_fast(t + 1.f), 1.f);
        acc[j] = __fmaf_rn(vv.y, s, acc[j]);
        t = exp2_fast(__fmaf_rn(dv.z, TWO_LOG2E, ec.z));
        s = __fmaf_rn(-2.f, rcp_fast(t + 1.f), 1.f);
        acc[j] = __fmaf_rn(vv.z, s, acc[j]);
        t = exp2_fast(__fmaf_rn(dv.w, TWO_LOG2E, ec.w));
        s = __fmaf_rn(-2.f, rcp_fast(t + 1.f), 1.f);
        acc[j] = __fmaf_rn(vv.w, s, acc[j]);
      }
    }
    __syncthreads();
  }
  long base = ((long)b * TD_ + d0 + dg * 4) * TE_ + e0 + e;
  score[base] = acc[0];
  score[base + TE_] = acc[1];
  score[base + 2 * TE_] = acc[2];
  score[base + 3 * TE_] = acc[3];
}

// ---------------- softmax in-place over last dim (512), one wave per row ----------
__global__ __launch_bounds__(64)
void softmax_kernel(float* __restrict__ s) {
  const long row = blockIdx.x;
  float* p = s + row * TE_;
  const int t = threadIdx.x;
  float x[8];
  float m = -1e30f;
#pragma unroll
  for (int k = 0; k < 8; ++k) {
    x[k] = p[t + k * 64];
    m = fmaxf(m, x[k]);
  }
#pragma unroll
  for (int off = 32; off; off >>= 1) m = fmaxf(m, __shfl_xor(m, off, 64));
  float sum = 0.f;
#pragma unroll
  for (int k = 0; k < 8; ++k) {
    x[k] = exp2_fast((x[k] - m) * LOG2E);
    sum += x[k];
  }
#pragma unroll
  for (int off = 32; off; off >>= 1) sum += __shfl_xor(sum, off, 64);
  const float r = rcp_fast(sum);
#pragma unroll
  for (int k = 0; k < 8; ++k) p[t + k * 64] = x[k] * r;
}

extern "C" void kernel_launch(void* const* d_in, const int* in_sizes, int n_in,
                              void* d_out, int out_size, void* d_ws, size_t ws_size,
                              hipStream_t stream) {
  const float* enc = (const float*)d_in[0];  // [B,TE,H]
  const float* dec = (const float*)d_in[1];  // [B,TD,H]
  const float* Wa  = (const float*)d_in[2];  // [H,H]
  const float* Ua  = (const float*)d_in[3];  // [H,H]
  const float* Va  = (const float*)d_in[4];  // [H,1]

  float* out  = (float*)d_out;
  float* ctx  = out;                               // [B,TD,H] = 262144 floats
  float* attn = out + (long)B_ * TD_ * H_;         // [B,TD,TE] = 524288 floats

  float* ep  = (float*)d_ws;                       // [B,TE,H] 4 MB
  float* dpp = ep + (long)B_ * TE_ * H_;           // [B,TD,H] 1 MB

  // enc_proj = enc @ W_a   (4096 x 256 x 256)
  gemm_f32<64, 64, 16, 4, 4><<<dim3((B_ * TE_) / 64, H_ / 64, 1), 256, 0, stream>>>(
      enc, Wa, ep, B_ * TE_, H_, H_, 0, 0, 0);
  // dec_proj = dec @ U_a   (1024 x 256 x 256)
  gemm_f32<64, 64, 16, 4, 4><<<dim3((B_ * TD_) / 64, H_ / 64, 1), 256, 0, stream>>>(
      dec, Ua, dpp, B_ * TD_, H_, H_, 0, 0, 0);
  // scores -> attention-weights slice of d_out
  score_kernel<<<dim3(TE_ / 32, TD_ / 32, B_), 256, 0, stream>>>(ep, dpp, Va, attn);
  // softmax in place
  softmax_kernel<<<dim3(B_ * TD_), 64, 0, stream>>>(attn);
  // context[b] = attn[b] @ enc[b]   (128 x 256 x 512, batched over B)
  gemm_f32<32, 64, 16, 2, 4><<<dim3(TD_ / 32, H_ / 64, B_), 256, 0, stream>>>(
      attn, enc, ctx, TD_, H_, TE_, (long)TD_ * TE_, (long)TE_ * H_, (long)TD_ * H_);
}

// Round 2
// 130.755 us; speedup vs baseline: 1.2490x; 1.2490x over previous
//
#include <hip/hip_runtime.h>
#include <hip/hip_bf16.h>

#ifndef __has_builtin
#define __has_builtin(x) 0
#endif

// ---- problem constants ----
constexpr int B_ = 8, TE_ = 512, TD_ = 128, H_ = 256;
constexpr float TWO_LOG2E = 2.8853900817779268f;   // 2*log2(e)
constexpr float LOG2E = 1.4426950408889634f;

__device__ __forceinline__ float exp2_fast(float x) {
#if __has_builtin(__builtin_amdgcn_exp2f)
  return __builtin_amdgcn_exp2f(x);     // v_exp_f32 (quarter rate)
#else
  return exp2f(x);
#endif
}
__device__ __forceinline__ float rcp_fast(float x) {
#if __has_builtin(__builtin_amdgcn_rcpf)
  return __builtin_amdgcn_rcpf(x);      // v_rcp_f32 (quarter rate)
#else
  return 1.0f / x;
#endif
}

// ================= fused dual projection GEMM =================
// Computes ep = (enc @ W) * 2log2e  [4096x256]  and dp = (dec @ U) * 2log2e [1024x256]
// in ONE launch. M-tiles 0..63 -> enc/W/ep, 64..79 -> dec/U/dp.
// BM=64, BN=32, BK=32, 256 threads, thread tile 4x2. grid (80, 8) = 640 blocks.
__global__ __launch_bounds__(256)
void proj_dual(const float* __restrict__ enc, const float* __restrict__ dec,
               const float* __restrict__ W, const float* __restrict__ U,
               float* __restrict__ ep, float* __restrict__ dp) {
  __shared__ __align__(16) float As[32][68];  // k-major A tile (64 rows + pad)
  __shared__ __align__(16) float Bs[32][36];
  const int tid = threadIdx.x;
  const int mt = blockIdx.x;
  const int col0 = blockIdx.y * 32;
  const float* A; const float* Bm; float* C; int row0;
  if (mt < 64) { A = enc; Bm = W; C = ep; row0 = mt * 64; }
  else         { A = dec; Bm = U; C = dp; row0 = (mt - 64) * 64; }
  const int tx = tid & 15;    // 16 col-groups of 2
  const int ty = tid >> 4;    // 16 row-groups of 4
  float acc[4][2] = {};

  for (int k0 = 0; k0 < H_; k0 += 32) {
    // stage A: 64 rows x 32 k = 512 float4, 2 per thread, transpose to k-major
#pragma unroll
    for (int i = 0; i < 2; ++i) {
      int idx = tid + i * 256;
      int r = idx >> 3, kg = (idx & 7) * 4;
      float4 a4 = *(const float4*)&A[(long)(row0 + r) * H_ + k0 + kg];
      As[kg + 0][r] = a4.x; As[kg + 1][r] = a4.y;
      As[kg + 2][r] = a4.z; As[kg + 3][r] = a4.w;
    }
    // stage B: 32 k x 32 n = 256 float4, 1 per thread
    {
      int kk = tid >> 3, c = (tid & 7) * 4;
      *(float4*)&Bs[kk][c] = *(const float4*)&Bm[(long)(k0 + kk) * H_ + col0 + c];
    }
    __syncthreads();
#pragma unroll
    for (int kk = 0; kk < 32; ++kk) {
      float4 a = *(const float4*)&As[kk][ty * 4];
      float2 b = *(const float2*)&Bs[kk][tx * 2];
      acc[0][0] = __fmaf_rn(a.x, b.x, acc[0][0]);
      acc[0][1] = __fmaf_rn(a.x, b.y, acc[0][1]);
      acc[1][0] = __fmaf_rn(a.y, b.x, acc[1][0]);
      acc[1][1] = __fmaf_rn(a.y, b.y, acc[1][1]);
      acc[2][0] = __fmaf_rn(a.z, b.x, acc[2][0]);
      acc[2][1] = __fmaf_rn(a.z, b.y, acc[2][1]);
      acc[3][0] = __fmaf_rn(a.w, b.x, acc[3][0]);
      acc[3][1] = __fmaf_rn(a.w, b.y, acc[3][1]);
    }
    __syncthreads();
  }
  // epilogue: fold the 2*log2e tanh prescale in here (saves VALU in score kernel)
#pragma unroll
  for (int m = 0; m < 4; ++m) {
    float2 o;
    o.x = acc[m][0] * TWO_LOG2E;
    o.y = acc[m][1] * TWO_LOG2E;
    *(float2*)&C[(long)(row0 + ty * 4 + m) * H_ + col0 + tx * 2] = o;
  }
}

// ================= score kernel =================
// score'[b,d,e] = sum_h (-2 v_h) * rcp(1 + exp2(ep'+dp'))   (ep',dp' prescaled)
// == reference score - sum_h(v_h): a constant shift, invisible to softmax.
// Tiles 32e x 16d, 256 threads (1e x 2d per thread), grid (16,8,8)=1024 blocks.
__global__ __launch_bounds__(256)
void score_kernel(const float* __restrict__ ep, const float* __restrict__ dp,
                  const float* __restrict__ v, float* __restrict__ score) {
  __shared__ __align__(16) float eps[32][68];
  __shared__ __align__(16) float dps[16][68];
  __shared__ __align__(16) float vs[64];      // -2*v chunk
  const int tid = threadIdx.x;
  const int b = blockIdx.z;
  const int e0 = blockIdx.x * 32;
  const int d0 = blockIdx.y * 16;
  const int e = tid & 31;
  const int dg = tid >> 5;   // 0..7, 2 d-rows each
  float acc0 = 0.f, acc1 = 0.f;

  for (int h0 = 0; h0 < H_; h0 += 64) {
#pragma unroll
    for (int i = 0; i < 2; ++i) {
      int idx = tid + i * 256;
      int r = idx >> 4, c = (idx & 15) << 2;
      *(float4*)&eps[r][c] = *(const float4*)&ep[(long)(b * TE_ + e0 + r) * H_ + h0 + c];
    }
    {
      int r = tid >> 4, c = (tid & 15) << 2;
      *(float4*)&dps[r][c] = *(const float4*)&dp[(long)(b * TD_ + d0 + r) * H_ + h0 + c];
    }
    if (tid < 16) {
      float4 v4 = *(const float4*)&v[h0 + tid * 4];
      float4 o; o.x = -2.f * v4.x; o.y = -2.f * v4.y; o.z = -2.f * v4.z; o.w = -2.f * v4.w;
      *(float4*)&vs[tid * 4] = o;
    }
    __syncthreads();
#pragma unroll
    for (int hh = 0; hh < 64; hh += 4) {
      float4 ev = *(const float4*)&eps[e][hh];
      float4 vv = *(const float4*)&vs[hh];
      float4 da = *(const float4*)&dps[dg * 2 + 0][hh];
      float4 db = *(const float4*)&dps[dg * 2 + 1][hh];
      float t;
      t = exp2_fast(ev.x + da.x); acc0 = __fmaf_rn(vv.x, rcp_fast(t + 1.f), acc0);
      t = exp2_fast(ev.y + da.y); acc0 = __fmaf_rn(vv.y, rcp_fast(t + 1.f), acc0);
      t = exp2_fast(ev.z + da.z); acc0 = __fmaf_rn(vv.z, rcp_fast(t + 1.f), acc0);
      t = exp2_fast(ev.w + da.w); acc0 = __fmaf_rn(vv.w, rcp_fast(t + 1.f), acc0);
      t = exp2_fast(ev.x + db.x); acc1 = __fmaf_rn(vv.x, rcp_fast(t + 1.f), acc1);
      t = exp2_fast(ev.y + db.y); acc1 = __fmaf_rn(vv.y, rcp_fast(t + 1.f), acc1);
      t = exp2_fast(ev.z + db.z); acc1 = __fmaf_rn(vv.z, rcp_fast(t + 1.f), acc1);
      t = exp2_fast(ev.w + db.w); acc1 = __fmaf_rn(vv.w, rcp_fast(t + 1.f), acc1);
    }
    __syncthreads();
  }
  long base = ((long)b * TD_ + d0 + dg * 2) * TE_ + e0 + e;
  score[base] = acc0;
  score[base + TE_] = acc1;
}

// ================= fused softmax + context =================
// Block: 256 threads = 4 waves; wave j softmaxes score row (d0+j) in-place
// (writing attention weights) then computes context row (d0+j).
// Thread: h-quad hq = tid&63 (h = 4*hq..4*hq+3). grid (TD/4=32, B=8).
__global__ __launch_bounds__(256)
void softmax_ctx(const float* __restrict__ enc, float* __restrict__ attn,
                 float* __restrict__ ctx) {
  __shared__ __align__(16) float ws[4][512];
  const int tid = threadIdx.x;
  const int b = blockIdx.y;
  const int d0 = blockIdx.x * 4;
  const int j = tid >> 6;       // wave id == d-row within block
  const int lane = tid & 63;

  // --- softmax of row d0+j over 512 encoder positions ---
  float* prow = attn + ((long)b * TD_ + d0 + j) * TE_;
  float x[8];
  float m = -1e30f;
#pragma unroll
  for (int k = 0; k < 8; ++k) { x[k] = prow[lane + 64 * k]; m = fmaxf(m, x[k]); }
#pragma unroll
  for (int off = 32; off; off >>= 1) m = fmaxf(m, __shfl_xor(m, off, 64));
  float s = 0.f;
#pragma unroll
  for (int k = 0; k < 8; ++k) { x[k] = exp2_fast((x[k] - m) * LOG2E); s += x[k]; }
#pragma unroll
  for (int off = 32; off; off >>= 1) s += __shfl_xor(s, off, 64);
  const float r = rcp_fast(s);
#pragma unroll
  for (int k = 0; k < 8; ++k) {
    float wv = x[k] * r;
    prow[lane + 64 * k] = wv;       // attention-weights output
    ws[j][lane + 64 * k] = wv;      // staged for context
  }
  __syncthreads();

  // --- context row: ctx[d0+j][4hq..] = sum_e w[e] * enc[e][4hq..] ---
  const int hq = lane;
  const float* encb = enc + (long)b * TE_ * H_ + hq * 4;
  float4 acc = {0.f, 0.f, 0.f, 0.f};
#pragma unroll 2
  for (int ee = 0; ee < TE_; ee += 4) {
    float4 wv = *(const float4*)&ws[j][ee];
    float4 e0 = *(const float4*)&encb[(long)(ee + 0) * H_];
    float4 e1 = *(const float4*)&encb[(long)(ee + 1) * H_];
    float4 e2 = *(const float4*)&encb[(long)(ee + 2) * H_];
    float4 e3 = *(const float4*)&encb[(long)(ee + 3) * H_];
    acc.x = __fmaf_rn(wv.x, e0.x, acc.x); acc.y = __fmaf_rn(wv.x, e0.y, acc.y);
    acc.z = __fmaf_rn(wv.x, e0.z, acc.z); acc.w = __fmaf_rn(wv.x, e0.w, acc.w);
    acc.x = __fmaf_rn(wv.y, e1.x, acc.x); acc.y = __fmaf_rn(wv.y, e1.y, acc.y);
    acc.z = __fmaf_rn(wv.y, e1.z, acc.z); acc.w = __fmaf_rn(wv.y, e1.w, acc.w);
    acc.x = __fmaf_rn(wv.z, e2.x, acc.x); acc.y = __fmaf_rn(wv.z, e2.y, acc.y);
    acc.z = __fmaf_rn(wv.z, e2.z, acc.z); acc.w = __fmaf_rn(wv.z, e2.w, acc.w);
    acc.x = __fmaf_rn(wv.w, e3.x, acc.x); acc.y = __fmaf_rn(wv.w, e3.y, acc.y);
    acc.z = __fmaf_rn(wv.w, e3.z, acc.z); acc.w = __fmaf_rn(wv.w, e3.w, acc.w);
  }
  *(float4*)&ctx[((long)b * TD_ + d0 + j) * H_ + hq * 4] = acc;
}

extern "C" void kernel_launch(void* const* d_in, const int* in_sizes, int n_in,
                              void* d_out, int out_size, void* d_ws, size_t ws_size,
                              hipStream_t stream) {
  const float* enc = (const float*)d_in[0];  // [B,TE,H]
  const float* dec = (const float*)d_in[1];  // [B,TD,H]
  const float* Wa  = (const float*)d_in[2];  // [H,H]
  const float* Ua  = (const float*)d_in[3];  // [H,H]
  const float* Va  = (const float*)d_in[4];  // [H,1]

  float* out  = (float*)d_out;
  float* ctx  = out;                           // [B,TD,H]
  float* attn = out + (long)B_ * TD_ * H_;     // [B,TD,TE]

  float* ep = (float*)d_ws;                    // [B*TE, H] prescaled
  float* dp = ep + (long)B_ * TE_ * H_;        // [B*TD, H] prescaled

  proj_dual<<<dim3(80, 8), 256, 0, stream>>>(enc, dec, Wa, Ua, ep, dp);
  score_kernel<<<dim3(TE_ / 32, TD_ / 16, B_), 256, 0, stream>>>(ep, dp, Va, attn);
  softmax_ctx<<<dim3(TD_ / 4, B_), 256, 0, stream>>>(enc, attn, ctx);
}

// Round 3
// 125.842 us; speedup vs baseline: 1.2978x; 1.0390x over previous
//
#include <hip/hip_runtime.h>
#include <hip/hip_bf16.h>

#ifndef __has_builtin
#define __has_builtin(x) 0
#endif

// ---- problem constants ----
constexpr int B_ = 8, TE_ = 512, TD_ = 128, H_ = 256;
constexpr float TWO_LOG2E = 2.8853900817779268f;   // 2*log2(e)
constexpr float LOG2E = 1.4426950408889634f;

__device__ __forceinline__ float exp2_fast(float x) {
#if __has_builtin(__builtin_amdgcn_exp2f)
  return __builtin_amdgcn_exp2f(x);     // v_exp_f32 (quarter rate, 8 cyc/wave)
#else
  return exp2f(x);
#endif
}
__device__ __forceinline__ float rcp_fast(float x) {
#if __has_builtin(__builtin_amdgcn_rcpf)
  return __builtin_amdgcn_rcpf(x);      // v_rcp_f32 (quarter rate)
#else
  return 1.0f / x;
#endif
}

// ================= fused dual projection GEMM =================
// ep = (enc @ W) * 2log2e [4096x256], dp = (dec @ U) * 2log2e [1024x256], one launch.
// BM=64, BN=32, BK=32, 256 threads, thread tile 4x2. grid (80, 8) = 640 blocks.
__global__ __launch_bounds__(256)
void proj_dual(const float* __restrict__ enc, const float* __restrict__ dec,
               const float* __restrict__ W, const float* __restrict__ U,
               float* __restrict__ ep, float* __restrict__ dp) {
  __shared__ __align__(16) float As[32][68];
  __shared__ __align__(16) float Bs[32][36];
  const int tid = threadIdx.x;
  const int mt = blockIdx.x;
  const int col0 = blockIdx.y * 32;
  const float* A; const float* Bm; float* C; int row0;
  if (mt < 64) { A = enc; Bm = W; C = ep; row0 = mt * 64; }
  else         { A = dec; Bm = U; C = dp; row0 = (mt - 64) * 64; }
  const int tx = tid & 15;
  const int ty = tid >> 4;
  float acc[4][2] = {};

  for (int k0 = 0; k0 < H_; k0 += 32) {
#pragma unroll
    for (int i = 0; i < 2; ++i) {
      int idx = tid + i * 256;
      int r = idx >> 3, kg = (idx & 7) * 4;
      float4 a4 = *(const float4*)&A[(long)(row0 + r) * H_ + k0 + kg];
      As[kg + 0][r] = a4.x; As[kg + 1][r] = a4.y;
      As[kg + 2][r] = a4.z; As[kg + 3][r] = a4.w;
    }
    {
      int kk = tid >> 3, c = (tid & 7) * 4;
      *(float4*)&Bs[kk][c] = *(const float4*)&Bm[(long)(k0 + kk) * H_ + col0 + c];
    }
    __syncthreads();
#pragma unroll
    for (int kk = 0; kk < 32; ++kk) {
      float4 a = *(const float4*)&As[kk][ty * 4];
      float2 b = *(const float2*)&Bs[kk][tx * 2];
      acc[0][0] = __fmaf_rn(a.x, b.x, acc[0][0]);
      acc[0][1] = __fmaf_rn(a.x, b.y, acc[0][1]);
      acc[1][0] = __fmaf_rn(a.y, b.x, acc[1][0]);
      acc[1][1] = __fmaf_rn(a.y, b.y, acc[1][1]);
      acc[2][0] = __fmaf_rn(a.z, b.x, acc[2][0]);
      acc[2][1] = __fmaf_rn(a.z, b.y, acc[2][1]);
      acc[3][0] = __fmaf_rn(a.w, b.x, acc[3][0]);
      acc[3][1] = __fmaf_rn(a.w, b.y, acc[3][1]);
    }
    __syncthreads();
  }
#pragma unroll
  for (int m = 0; m < 4; ++m) {
    float2 o;
    o.x = acc[m][0] * TWO_LOG2E;
    o.y = acc[m][1] * TWO_LOG2E;
    *(float2*)&C[(long)(row0 + ty * 4 + m) * H_ + col0 + tx * 2] = o;
  }
}

// ================= score kernel =================
// sc[b,d,e] = sum_h (-2 v_h) * rcp(1 + exp2(ep'+dp'))  (prescaled inputs)
// == reference score minus sum_h(v_h): constant shift, invisible to softmax.
// Tiles 32e x 16d, 256 threads (1e x 2d), grid (16,8,8)=1024 blocks (4/CU).
__global__ __launch_bounds__(256)
void score_kernel(const float* __restrict__ ep, const float* __restrict__ dp,
                  const float* __restrict__ v, float* __restrict__ sc) {
  __shared__ __align__(16) float eps[32][68];
  __shared__ __align__(16) float dps[16][68];
  __shared__ __align__(16) float vs[64];
  const int tid = threadIdx.x;
  const int b = blockIdx.z;
  const int e0 = blockIdx.x * 32;
  const int d0 = blockIdx.y * 16;
  const int e = tid & 31;
  const int dg = tid >> 5;
  float acc0 = 0.f, acc1 = 0.f;

  for (int h0 = 0; h0 < H_; h0 += 64) {
#pragma unroll
    for (int i = 0; i < 2; ++i) {
      int idx = tid + i * 256;
      int r = idx >> 4, c = (idx & 15) << 2;
      *(float4*)&eps[r][c] = *(const float4*)&ep[(long)(b * TE_ + e0 + r) * H_ + h0 + c];
    }
    {
      int r = tid >> 4, c = (tid & 15) << 2;
      *(float4*)&dps[r][c] = *(const float4*)&dp[(long)(b * TD_ + d0 + r) * H_ + h0 + c];
    }
    if (tid < 16) {
      float4 v4 = *(const float4*)&v[h0 + tid * 4];
      float4 o; o.x = -2.f * v4.x; o.y = -2.f * v4.y; o.z = -2.f * v4.z; o.w = -2.f * v4.w;
      *(float4*)&vs[tid * 4] = o;
    }
    __syncthreads();
#pragma unroll
    for (int hh = 0; hh < 64; hh += 4) {
      float4 ev = *(const float4*)&eps[e][hh];
      float4 vv = *(const float4*)&vs[hh];
      float4 da = *(const float4*)&dps[dg * 2 + 0][hh];
      float4 db = *(const float4*)&dps[dg * 2 + 1][hh];
      float t;
      t = exp2_fast(ev.x + da.x); acc0 = __fmaf_rn(vv.x, rcp_fast(t + 1.f), acc0);
      t = exp2_fast(ev.y + da.y); acc0 = __fmaf_rn(vv.y, rcp_fast(t + 1.f), acc0);
      t = exp2_fast(ev.z + da.z); acc0 = __fmaf_rn(vv.z, rcp_fast(t + 1.f), acc0);
      t = exp2_fast(ev.w + da.w); acc0 = __fmaf_rn(vv.w, rcp_fast(t + 1.f), acc0);
      t = exp2_fast(ev.x + db.x); acc1 = __fmaf_rn(vv.x, rcp_fast(t + 1.f), acc1);
      t = exp2_fast(ev.y + db.y); acc1 = __fmaf_rn(vv.y, rcp_fast(t + 1.f), acc1);
      t = exp2_fast(ev.z + db.z); acc1 = __fmaf_rn(vv.z, rcp_fast(t + 1.f), acc1);
      t = exp2_fast(ev.w + db.w); acc1 = __fmaf_rn(vv.w, rcp_fast(t + 1.f), acc1);
    }
    __syncthreads();
  }
  long base = ((long)b * TD_ + d0 + dg * 2) * TE_ + e0 + e;
  sc[base] = acc0;
  sc[base + TE_] = acc1;
}

// ================= fused softmax + context, LDS-shared enc =================
// grid (TD/4=32, H/128=2, B=8) = 512 blocks (2/CU), 256 threads = 4 waves.
// Wave j: softmax of score row (d0+j) from sc (wave-reduce in regs); writes attn
// only when blockIdx.y==0 (the h-split twin reads sc, never attn -> no race).
// Then ctx rows d0..d0+3 for h-cols [h0,h0+128): enc staged in LDS in 64e
// chunks, SHARED across the 4 d-rows (4x less L2 traffic than per-wave streams).
__global__ __launch_bounds__(256)
void softmax_ctx(const float* __restrict__ enc, const float* __restrict__ sc,
                 float* __restrict__ attn, float* __restrict__ ctx) {
  __shared__ __align__(16) float ws4[4][512];
  __shared__ __align__(16) float encs[64][128];   // 32 KB chunk
  const int tid = threadIdx.x;
  const int b = blockIdx.z;
  const int h0 = blockIdx.y * 128;
  const int d0 = blockIdx.x * 4;
  const int j = tid >> 6;
  const int lane = tid & 63;

  // --- softmax (one wave per d-row) ---
  const float* srow = sc + ((long)b * TD_ + d0 + j) * TE_;
  float x[8];
  float m = -1e30f;
#pragma unroll
  for (int k = 0; k < 8; ++k) { x[k] = srow[lane + 64 * k]; m = fmaxf(m, x[k]); }
#pragma unroll
  for (int off = 32; off; off >>= 1) m = fmaxf(m, __shfl_xor(m, off, 64));
  float s = 0.f;
#pragma unroll
  for (int k = 0; k < 8; ++k) { x[k] = exp2_fast((x[k] - m) * LOG2E); s += x[k]; }
#pragma unroll
  for (int off = 32; off; off >>= 1) s += __shfl_xor(s, off, 64);
  const float r = rcp_fast(s);
  float* arow = attn + ((long)b * TD_ + d0 + j) * TE_;
#pragma unroll
  for (int k = 0; k < 8; ++k) {
    float wv = x[k] * r;
    ws4[j][lane + 64 * k] = wv;                  // wave-private row, no sync needed
    if (blockIdx.y == 0) arow[lane + 64 * k] = wv;  // attention-weights output
  }

  // --- context: acc over e in 64-wide LDS-staged chunks ---
  float2 acc = {0.f, 0.f};
  for (int c0 = 0; c0 < TE_; c0 += 64) {
    __syncthreads();   // encs reuse guard (also covers first-iter ws4 ordering)
#pragma unroll
    for (int k = 0; k < 8; ++k) {
      int idx = tid + k * 256;                   // 2048 float4 = 64e x 128h
      int e = idx >> 5, q = (idx & 31) << 2;
      *(float4*)&encs[e][q] =
          *(const float4*)&enc[((long)(b * TE_ + c0 + e)) * H_ + h0 + q];
    }
    __syncthreads();
#pragma unroll 4
    for (int ee = 0; ee < 64; ee += 4) {
      float4 wv = *(const float4*)&ws4[j][c0 + ee];   // wave-uniform broadcast
      float2 e0v = *(const float2*)&encs[ee + 0][lane * 2];
      float2 e1v = *(const float2*)&encs[ee + 1][lane * 2];
      float2 e2v = *(const float2*)&encs[ee + 2][lane * 2];
      float2 e3v = *(const float2*)&encs[ee + 3][lane * 2];
      acc.x = __fmaf_rn(wv.x, e0v.x, acc.x); acc.y = __fmaf_rn(wv.x, e0v.y, acc.y);
      acc.x = __fmaf_rn(wv.y, e1v.x, acc.x); acc.y = __fmaf_rn(wv.y, e1v.y, acc.y);
      acc.x = __fmaf_rn(wv.z, e2v.x, acc.x); acc.y = __fmaf_rn(wv.z, e2v.y, acc.y);
      acc.x = __fmaf_rn(wv.w, e3v.x, acc.x); acc.y = __fmaf_rn(wv.w, e3v.y, acc.y);
    }
  }
  *(float2*)&ctx[((long)b * TD_ + d0 + j) * H_ + h0 + lane * 2] = acc;
}

extern "C" void kernel_launch(void* const* d_in, const int* in_sizes, int n_in,
                              void* d_out, int out_size, void* d_ws, size_t ws_size,
                              hipStream_t stream) {
  const float* enc = (const float*)d_in[0];  // [B,TE,H]
  const float* dec = (const float*)d_in[1];  // [B,TD,H]
  const float* Wa  = (const float*)d_in[2];  // [H,H]
  const float* Ua  = (const float*)d_in[3];  // [H,H]
  const float* Va  = (const float*)d_in[4];  // [H,1]

  float* out  = (float*)d_out;
  float* ctx  = out;                           // [B,TD,H]
  float* attn = out + (long)B_ * TD_ * H_;     // [B,TD,TE]

  float* ep = (float*)d_ws;                    // [B*TE,H] prescaled by 2log2e
  float* dp = ep + (long)B_ * TE_ * H_;        // [B*TD,H] prescaled
  float* sc = dp + (long)B_ * TD_ * H_;        // [B,TD,TE] raw (shifted) scores

  proj_dual<<<dim3(80, 8), 256, 0, stream>>>(enc, dec, Wa, Ua, ep, dp);
  score_kernel<<<dim3(TE_ / 32, TD_ / 16, B_), 256, 0, stream>>>(ep, dp, Va, sc);
  softmax_ctx<<<dim3(TD_ / 4, H_ / 128, B_), 256, 0, stream>>>(enc, sc, attn, ctx);
}

// Round 4
// 108.872 us; speedup vs baseline: 1.5000x; 1.1559x over previous
//
#include <hip/hip_runtime.h>
#include <hip/hip_bf16.h>

#ifndef __has_builtin
#define __has_builtin(x) 0
#endif

// ---- problem constants ----
constexpr int B_ = 8, TE_ = 512, TD_ = 128, H_ = 256;
constexpr float TWO_LOG2E = 2.8853900817779268f;   // 2*log2(e)
constexpr float LOG2E = 1.4426950408889634f;

typedef float  vf2    __attribute__((ext_vector_type(2)));
typedef short  bf16x8 __attribute__((ext_vector_type(8)));
typedef float  f32x4  __attribute__((ext_vector_type(4)));

__device__ __forceinline__ float exp2_fast(float x) {
#if __has_builtin(__builtin_amdgcn_exp2f)
  return __builtin_amdgcn_exp2f(x);     // v_exp_f32 (quarter rate)
#else
  return exp2f(x);
#endif
}
__device__ __forceinline__ float rcp_fast(float x) {
#if __has_builtin(__builtin_amdgcn_rcpf)
  return __builtin_amdgcn_rcpf(x);      // v_rcp_f32 (quarter rate)
#else
  return 1.0f / x;
#endif
}
__device__ __forceinline__ vf2 fma2(vf2 a, vf2 b, vf2 c) {
#if __has_builtin(__builtin_elementwise_fma)
  return __builtin_elementwise_fma(a, b, c);   // v_pk_fma_f32
#else
  vf2 r; r.x = __fmaf_rn(a.x, b.x, c.x); r.y = __fmaf_rn(a.y, b.y, c.y); return r;
#endif
}
// split fp32 -> bf16 hi + bf16 lo (truncation; x ~= hi + lo to ~2^-16 rel)
__device__ __forceinline__ void bf16split(float x, unsigned short& hi, unsigned short& lo) {
  unsigned u = __float_as_uint(x);
  hi = (unsigned short)(u >> 16);
  float hif = __uint_as_float((unsigned)hi << 16);
  lo = (unsigned short)(__float_as_uint(x - hif) >> 16);
}

// ================= MFMA projection: ep=(enc@W)*c, dp=(dec@U)*c =================
// Split-bf16 (3 products). Block tile 32m x 32n, 4 waves (each a 16x16 C tile),
// K chunks of 32. grid (160, 8) = 1280 blocks. mt<128 -> enc/W/ep else dec/U/dp.
__global__ __launch_bounds__(256)
void proj_mfma(const float* __restrict__ enc, const float* __restrict__ dec,
               const float* __restrict__ W, const float* __restrict__ U,
               float* __restrict__ ep, float* __restrict__ dp) {
  __shared__ unsigned short Ah[32][40], Al[32][40], Bh[32][40], Bl[32][40];
  const int tid = threadIdx.x;
  const int mt = blockIdx.x;
  const int n0 = blockIdx.y * 32;
  const float* A; const float* Bm; float* C; int row0;
  if (mt < 128) { A = enc; Bm = W; C = ep; row0 = mt * 32; }
  else          { A = dec; Bm = U; C = dp; row0 = (mt - 128) * 32; }
  const int w = tid >> 6, lane = tid & 63;
  const int mw = (w & 1) * 16, nw = (w >> 1) * 16;
  const int quad = lane >> 4, l16 = lane & 15;
  const int am = tid >> 3, ak = (tid & 7) * 4;    // A staging: row am, k quad ak
  const int bn = tid & 31, bk = (tid >> 5) * 4;   // B staging: col bn, 4 k's

  f32x4 acc = {0.f, 0.f, 0.f, 0.f};
  for (int k0 = 0; k0 < H_; k0 += 32) {
    // stage A tile (32m x 32k), fp32 -> hi/lo bf16, k-contiguous rows
    float4 a4 = *(const float4*)&A[(long)(row0 + am) * H_ + k0 + ak];
    unsigned short h0, l0, h1, l1, h2, l2, h3, l3;
    bf16split(a4.x, h0, l0); bf16split(a4.y, h1, l1);
    bf16split(a4.z, h2, l2); bf16split(a4.w, h3, l3);
    *(ushort4*)&Ah[am][ak] = make_ushort4(h0, h1, h2, h3);
    *(ushort4*)&Al[am][ak] = make_ushort4(l0, l1, l2, l3);
    // stage B tile (32k x 32n) transposed to [n][k]
    float b0 = Bm[(long)(k0 + bk + 0) * H_ + n0 + bn];
    float b1 = Bm[(long)(k0 + bk + 1) * H_ + n0 + bn];
    float b2 = Bm[(long)(k0 + bk + 2) * H_ + n0 + bn];
    float b3 = Bm[(long)(k0 + bk + 3) * H_ + n0 + bn];
    bf16split(b0, h0, l0); bf16split(b1, h1, l1);
    bf16split(b2, h2, l2); bf16split(b3, h3, l3);
    *(ushort4*)&Bh[bn][bk] = make_ushort4(h0, h1, h2, h3);
    *(ushort4*)&Bl[bn][bk] = make_ushort4(l0, l1, l2, l3);
    __syncthreads();
    // fragments: A[m=l16][k=quad*8+j], B[k=quad*8+j][n=l16]
    bf16x8 ah = *(const bf16x8*)&Ah[mw + l16][quad * 8];
    bf16x8 al = *(const bf16x8*)&Al[mw + l16][quad * 8];
    bf16x8 bh = *(const bf16x8*)&Bh[nw + l16][quad * 8];
    bf16x8 bl = *(const bf16x8*)&Bl[nw + l16][quad * 8];
    acc = __builtin_amdgcn_mfma_f32_16x16x32_bf16(ah, bh, acc, 0, 0, 0);
    acc = __builtin_amdgcn_mfma_f32_16x16x32_bf16(ah, bl, acc, 0, 0, 0);
    acc = __builtin_amdgcn_mfma_f32_16x16x32_bf16(al, bh, acc, 0, 0, 0);
    __syncthreads();
  }
  // C/D: row = quad*4+reg, col = l16; epilogue folds tanh prescale
#pragma unroll
  for (int r = 0; r < 4; ++r)
    C[(long)(row0 + mw + quad * 4 + r) * H_ + n0 + nw + l16] = acc[r] * TWO_LOG2E;
}

// ================= score kernel (packed fp32 math) =================
// sc[b,d,e] = sum_h (-2 v_h) * rcp(1 + exp2(ep'+dp'))  (prescaled inputs)
// == reference score minus const shift (invisible to softmax).
// Tiles 32e x 16d, 256 threads (1e x 2d), grid (16,8,8)=1024 blocks.
__global__ __launch_bounds__(256)
void score_kernel(const float* __restrict__ ep, const float* __restrict__ dp,
                  const float* __restrict__ v, float* __restrict__ sc) {
  __shared__ __align__(16) float eps[32][68];
  __shared__ __align__(16) float dps[16][68];
  __shared__ __align__(16) float vs[64];
  const int tid = threadIdx.x;
  const int b = blockIdx.z;
  const int e0 = blockIdx.x * 32;
  const int d0 = blockIdx.y * 16;
  const int e = tid & 31;
  const int dg = tid >> 5;
  vf2 acc0 = {0.f, 0.f}, acc1 = {0.f, 0.f};

  for (int h0 = 0; h0 < H_; h0 += 64) {
#pragma unroll
    for (int i = 0; i < 2; ++i) {
      int idx = tid + i * 256;
      int r = idx >> 4, c = (idx & 15) << 2;
      *(float4*)&eps[r][c] = *(const float4*)&ep[(long)(b * TE_ + e0 + r) * H_ + h0 + c];
    }
    {
      int r = tid >> 4, c = (tid & 15) << 2;
      *(float4*)&dps[r][c] = *(const float4*)&dp[(long)(b * TD_ + d0 + r) * H_ + h0 + c];
    }
    if (tid < 16) {
      float4 v4 = *(const float4*)&v[h0 + tid * 4];
      float4 o; o.x = -2.f * v4.x; o.y = -2.f * v4.y; o.z = -2.f * v4.z; o.w = -2.f * v4.w;
      *(float4*)&vs[tid * 4] = o;
    }
    __syncthreads();
    const vf2 one2 = {1.f, 1.f};
#pragma unroll
    for (int hh = 0; hh < 64; hh += 4) {
      vf2 ev0 = *(const vf2*)&eps[e][hh];
      vf2 ev1 = *(const vf2*)&eps[e][hh + 2];
      vf2 vv0 = *(const vf2*)&vs[hh];
      vf2 vv1 = *(const vf2*)&vs[hh + 2];
      vf2 da0 = *(const vf2*)&dps[dg * 2 + 0][hh];
      vf2 da1 = *(const vf2*)&dps[dg * 2 + 0][hh + 2];
      vf2 db0 = *(const vf2*)&dps[dg * 2 + 1][hh];
      vf2 db1 = *(const vf2*)&dps[dg * 2 + 1][hh + 2];
      vf2 g0 = ev0 + da0, g1 = ev1 + da1;      // v_pk_add_f32
      vf2 h0 = ev0 + db0, h1 = ev1 + db1;
      vf2 t0, t1, u0, u1;
      t0.x = exp2_fast(g0.x); t0.y = exp2_fast(g0.y);
      t1.x = exp2_fast(g1.x); t1.y = exp2_fast(g1.y);
      u0.x = exp2_fast(h0.x); u0.y = exp2_fast(h0.y);
      u1.x = exp2_fast(h1.x); u1.y = exp2_fast(h1.y);
      t0 = t0 + one2; t1 = t1 + one2; u0 = u0 + one2; u1 = u1 + one2;
      vf2 r0, r1, s0, s1;
      r0.x = rcp_fast(t0.x); r0.y = rcp_fast(t0.y);
      r1.x = rcp_fast(t1.x); r1.y = rcp_fast(t1.y);
      s0.x = rcp_fast(u0.x); s0.y = rcp_fast(u0.y);
      s1.x = rcp_fast(u1.x); s1.y = rcp_fast(u1.y);
      acc0 = fma2(vv0, r0, acc0); acc0 = fma2(vv1, r1, acc0);
      acc1 = fma2(vv0, s0, acc1); acc1 = fma2(vv1, s1, acc1);
    }
    __syncthreads();
  }
  long base = ((long)b * TD_ + d0 + dg * 2) * TE_ + e0 + e;
  sc[base] = acc0.x + acc0.y;
  sc[base + TE_] = acc1.x + acc1.y;
}

// ================= softmax: sc row -> attn row, one wave per row =================
__global__ __launch_bounds__(64)
void softmax_kernel(const float* __restrict__ sc, float* __restrict__ attn) {
  const long row = blockIdx.x;
  const float* pin = sc + row * TE_;
  float* pout = attn + row * TE_;
  const int t = threadIdx.x;
  float x[8];
  float m = -1e30f;
#pragma unroll
  for (int k = 0; k < 8; ++k) { x[k] = pin[t + 64 * k]; m = fmaxf(m, x[k]); }
#pragma unroll
  for (int off = 32; off; off >>= 1) m = fmaxf(m, __shfl_xor(m, off, 64));
  float s = 0.f;
#pragma unroll
  for (int k = 0; k < 8; ++k) { x[k] = exp2_fast((x[k] - m) * LOG2E); s += x[k]; }
#pragma unroll
  for (int off = 32; off; off >>= 1) s += __shfl_xor(s, off, 64);
  const float r = rcp_fast(s);
#pragma unroll
  for (int k = 0; k < 8; ++k) pout[t + 64 * k] = x[k] * r;
}

// ================= MFMA context: ctx[b] = attn[b] @ enc[b] =================
// M=128, N=256, K=512 per batch. Block tile 32m x 32n, K chunks of 32.
// grid (4, 8, 8) = 256 blocks. Same split-bf16 3-product scheme.
__global__ __launch_bounds__(256)
void ctx_mfma(const float* __restrict__ attn, const float* __restrict__ enc,
              float* __restrict__ ctx) {
  __shared__ unsigned short Ah[32][40], Al[32][40], Bh[32][40], Bl[32][40];
  const int tid = threadIdx.x;
  const int m0 = blockIdx.x * 32;
  const int n0 = blockIdx.y * 32;
  const int b = blockIdx.z;
  const float* A = attn + (long)b * TD_ * TE_;   // [128][512]
  const float* E = enc + (long)b * TE_ * H_;     // [512][256]
  const int w = tid >> 6, lane = tid & 63;
  const int mw = (w & 1) * 16, nw = (w >> 1) * 16;
  const int quad = lane >> 4, l16 = lane & 15;
  const int am = tid >> 3, ak = (tid & 7) * 4;
  const int bn = tid & 31, bk = (tid >> 5) * 4;

  f32x4 acc = {0.f, 0.f, 0.f, 0.f};
  for (int k0 = 0; k0 < TE_; k0 += 32) {
    float4 a4 = *(const float4*)&A[(long)(m0 + am) * TE_ + k0 + ak];
    unsigned short h0, l0, h1, l1, h2, l2, h3, l3;
    bf16split(a4.x, h0, l0); bf16split(a4.y, h1, l1);
    bf16split(a4.z, h2, l2); bf16split(a4.w, h3, l3);
    *(ushort4*)&Ah[am][ak] = make_ushort4(h0, h1, h2, h3);
    *(ushort4*)&Al[am][ak] = make_ushort4(l0, l1, l2, l3);
    float b0 = E[(long)(k0 + bk + 0) * H_ + n0 + bn];
    float b1 = E[(long)(k0 + bk + 1) * H_ + n0 + bn];
    float b2 = E[(long)(k0 + bk + 2) * H_ + n0 + bn];
    float b3 = E[(long)(k0 + bk + 3) * H_ + n0 + bn];
    bf16split(b0, h0, l0); bf16split(b1, h1, l1);
    bf16split(b2, h2, l2); bf16split(b3, h3, l3);
    *(ushort4*)&Bh[bn][bk] = make_ushort4(h0, h1, h2, h3);
    *(ushort4*)&Bl[bn][bk] = make_ushort4(l0, l1, l2, l3);
    __syncthreads();
    bf16x8 ah = *(const bf16x8*)&Ah[mw + l16][quad * 8];
    bf16x8 al = *(const bf16x8*)&Al[mw + l16][quad * 8];
    bf16x8 bh = *(const bf16x8*)&Bh[nw + l16][quad * 8];
    bf16x8 bl = *(const bf16x8*)&Bl[nw + l16][quad * 8];
    acc = __builtin_amdgcn_mfma_f32_16x16x32_bf16(ah, bh, acc, 0, 0, 0);
    acc = __builtin_amdgcn_mfma_f32_16x16x32_bf16(ah, bl, acc, 0, 0, 0);
    acc = __builtin_amdgcn_mfma_f32_16x16x32_bf16(al, bh, acc, 0, 0, 0);
    __syncthreads();
  }
#pragma unroll
  for (int r = 0; r < 4; ++r)
    ctx[((long)b * TD_ + m0 + mw + quad * 4 + r) * H_ + n0 + nw + l16] = acc[r];
}

extern "C" void kernel_launch(void* const* d_in, const int* in_sizes, int n_in,
                              void* d_out, int out_size, void* d_ws, size_t ws_size,
                              hipStream_t stream) {
  const float* enc = (const float*)d_in[0];  // [B,TE,H]
  const float* dec = (const float*)d_in[1];  // [B,TD,H]
  const float* Wa  = (const float*)d_in[2];  // [H,H]
  const float* Ua  = (const float*)d_in[3];  // [H,H]
  const float* Va  = (const float*)d_in[4];  // [H,1]

  float* out  = (float*)d_out;
  float* ctx  = out;                           // [B,TD,H]
  float* attn = out + (long)B_ * TD_ * H_;     // [B,TD,TE]

  float* ep = (float*)d_ws;                    // [B*TE,H] prescaled by 2log2e
  float* dp = ep + (long)B_ * TE_ * H_;        // [B*TD,H] prescaled
  float* sc = dp + (long)B_ * TD_ * H_;        // [B,TD,TE] shifted scores

  proj_mfma<<<dim3(160, 8), 256, 0, stream>>>(enc, dec, Wa, Ua, ep, dp);
  score_kernel<<<dim3(TE_ / 32, TD_ / 16, B_), 256, 0, stream>>>(ep, dp, Va, sc);
  softmax_kernel<<<dim3(B_ * TD_), 64, 0, stream>>>(sc, attn);
  ctx_mfma<<<dim3(TD_ / 32, H_ / 32, B_), 256, 0, stream>>>(attn, enc, ctx);
}